// Round 1
// baseline (4289.593 us; speedup 1.0000x reference)
//
#include <hip/hip_runtime.h>

// ---------------------------------------------------------------------------
// ConversationLSTMStack: B=64, S=2048, D=H=768, L=2.
// Identities: h fed to cells is always zeros -> W_hh unused;
//   gates = x @ W_ih^T + (b_ih+b_hh); recurrence is elementwise c = f*c + i*g
//   (layer0: speaker-change resets c first).
// Structure (this round): per-chunk layer interleave
//   cast(chunk) -> GEMM0 -> scan0 (emits h0 bf16 chunk) -> GEMM1 -> scan1
// GEMM applies bias+activation in the epilogue (each 128-col tile is within one
// gate plane), so the scan is a pure  c = f*c + a*g ; h = o*tanh(c)  stream.
// Chunked fp32 activation buffer (100 MB @ chunk=128) stays L3-resident.
// ---------------------------------------------------------------------------

typedef __attribute__((ext_vector_type(8))) short short8;
typedef __attribute__((ext_vector_type(4))) float floatx4;

#define B_ 64
#define S_ 2048
#define K_ 768
#define NG_ 3072  // 4*H

__device__ __forceinline__ unsigned short f2bf(float f) {
  unsigned int u = __builtin_bit_cast(unsigned int, f);
  u += 0x7fffu + ((u >> 16) & 1u);  // RTNE
  return (unsigned short)(u >> 16);
}

__device__ __forceinline__ float fsig(float x) {
  return __builtin_amdgcn_rcpf(1.f + __expf(-x));
}
__device__ __forceinline__ float mytanh(float x) {
  float e = __expf(-2.f * fabsf(x));
  float r = (1.f - e) * __builtin_amdgcn_rcpf(1.f + e);
  return __builtin_copysignf(r, x);
}

__device__ __forceinline__ void async16(const void* g, void* l) {
  __builtin_amdgcn_global_load_lds((__attribute__((address_space(1))) void*)g,
                                   (__attribute__((address_space(3))) void*)l,
                                   16, 0, 0);
}

// ---------------- prep kernels ----------------

__global__ __launch_bounds__(256) void prep_w(const float4* __restrict__ w4,
                                              ushort4* __restrict__ o4) {
  int idx = blockIdx.x * 256 + threadIdx.x;  // 2*3072*768/4 elems
  float4 v = w4[idx];
  ushort4 r;
  r.x = f2bf(v.x); r.y = f2bf(v.y); r.z = f2bf(v.z); r.w = f2bf(v.w);
  o4[idx] = r;
}

__global__ __launch_bounds__(256) void prep_small(const float* __restrict__ bih,
                                                  const float* __restrict__ bhh,
                                                  const int* __restrict__ parts,
                                                  float* __restrict__ bias,
                                                  int* __restrict__ rst) {
  int tid = blockIdx.x * 256 + threadIdx.x;  // 8192 threads
  if (tid < 2 * NG_) {
    bias[tid] = bih[tid] + bhh[tid];
  } else {
    int t = tid - 2 * NG_;
    rst[t] = (t == 0) ? 1 : ((parts[t] != parts[t - 1]) ? 1 : 0);
  }
}

// x [B,S,768] fp32 -> Ah bf16, rows m = dt*B + b (K-contiguous), chunk slice
__global__ __launch_bounds__(256) void cast_x(const float4* __restrict__ x4,
                                              ushort4* __restrict__ a4, int t0) {
  int idx = blockIdx.x * 256 + threadIdx.x;  // chunk*64*192
  int m = idx / 192;
  int j = idx - m * 192;
  int b = m & 63, dt = m >> 6;
  float4 v = x4[((size_t)b * S_ + t0 + dt) * 192 + j];
  ushort4 r;
  r.x = f2bf(v.x); r.y = f2bf(v.y); r.z = f2bf(v.z); r.w = f2bf(v.w);
  a4[(size_t)m * 192 + j] = r;
}

// ---------------- GEMM: G[m,n] = act( sum_k A[m,k]*W[n,k] + bias[n] ) --------
// 128x128 block tile, BK=64, 4 waves (2x2 of 64x64), 16x16x32 bf16 MFMA.
// LDS tiles [128 rows][64 cols] bf16, 16B chunks XOR-swizzled by (row&7).
// Epilogue: block-uniform activation (cols 1536..2303 -> tanh, else sigmoid).
__global__ __launch_bounds__(256) void gemm_bt(const unsigned short* __restrict__ A,
                                               const unsigned short* __restrict__ Bw,
                                               const float* __restrict__ bias,
                                               float* __restrict__ C) {
  __shared__ __align__(16) unsigned short At[128 * 64];
  __shared__ __align__(16) unsigned short Bt[128 * 64];
  const int tid = threadIdx.x;
  const int lane = tid & 63;
  const int wave = tid >> 6;
  const int wm = wave & 1, wn = wave >> 1;
  const int bm = blockIdx.x, bn = blockIdx.y;

  floatx4 acc[4][4] = {};

  const int rl = tid >> 3;  // 0..31
  const int cp = tid & 7;   // physical 16B chunk
  const size_t arow0 = (size_t)bm * 128;
  const size_t brow0 = (size_t)bn * 128;
  const int l15 = lane & 15, q = lane >> 4, sw = lane & 7;

  for (int kt = 0; kt < K_ / 64; ++kt) {
    const int k0 = kt * 64;
#pragma unroll
    for (int j = 0; j < 4; ++j) {
      int r = j * 32 + rl;
      int cl = cp ^ (r & 7);
      async16(A + (arow0 + r) * K_ + k0 + cl * 8, &At[r * 64 + cp * 8]);
      async16(Bw + (brow0 + r) * K_ + k0 + cl * 8, &Bt[r * 64 + cp * 8]);
    }
    __syncthreads();
#pragma unroll
    for (int ks = 0; ks < 2; ++ks) {
      short8 af[4], bf[4];
#pragma unroll
      for (int i = 0; i < 4; ++i) {
        int am = wm * 64 + i * 16 + l15;
        int bn_ = wn * 64 + i * 16 + l15;
        af[i] = *(const short8*)&At[am * 64 + ((ks * 4 + q) ^ sw) * 8];
        bf[i] = *(const short8*)&Bt[bn_ * 64 + ((ks * 4 + q) ^ sw) * 8];
      }
#pragma unroll
      for (int mi = 0; mi < 4; ++mi)
#pragma unroll
        for (int ni = 0; ni < 4; ++ni)
          acc[mi][ni] = __builtin_amdgcn_mfma_f32_16x16x32_bf16(
              af[mi], bf[ni], acc[mi][ni], 0, 0, 0);
    }
    __syncthreads();
  }

  // epilogue: D[row=q*4+r][col=lane&15]; bias + activation, block-uniform kind
  const bool isg = (bn >= 12) && (bn < 18);  // g-gate plane: cols [1536,2304)
  if (isg) {
#pragma unroll
    for (int ni = 0; ni < 4; ++ni) {
      int col = bn * 128 + wn * 64 + ni * 16 + l15;
      float bs = bias[col];
#pragma unroll
      for (int mi = 0; mi < 4; ++mi) {
        int row = bm * 128 + wm * 64 + mi * 16 + q * 4;
#pragma unroll
        for (int r = 0; r < 4; ++r)
          C[(size_t)(row + r) * NG_ + col] = mytanh(acc[mi][ni][r] + bs);
      }
    }
  } else {
#pragma unroll
    for (int ni = 0; ni < 4; ++ni) {
      int col = bn * 128 + wn * 64 + ni * 16 + l15;
      float bs = bias[col];
#pragma unroll
      for (int mi = 0; mi < 4; ++mi) {
        int row = bm * 128 + wm * 64 + mi * 16 + q * 4;
#pragma unroll
        for (int r = 0; r < 4; ++r)
          C[(size_t)(row + r) * NG_ + col] = fsig(acc[mi][ni][r] + bs);
      }
    }
  }
}

// ---------------- scan: c = f*c + a*g ; h = o*tanh(c) over a time chunk -----
// G holds pre-activated planes a=sig(i), f=sig(f), g=tanh(g), o=sig(o).
template <int LAYER>
__global__ __launch_bounds__(64) void scan_kernel(
    const float* __restrict__ G, int Tc, int t0, const int* __restrict__ rst,
    float* __restrict__ carry, unsigned short* __restrict__ h0c,
    float* __restrict__ out, float* __restrict__ hfin, float* __restrict__ cfin) {
  const int b = blockIdx.x / 12;
  const int h = (blockIdx.x % 12) * 64 + threadIdx.x;
  const int ci = b * K_ + h;
  float c = (t0 == 0) ? 0.f : carry[ci];

  float va[8], vf[8], vg[8], vo[8];
#pragma unroll
  for (int d = 0; d < 8; ++d) {
    size_t base = ((size_t)(d * B_ + b)) * NG_ + h;
    va[d] = G[base];
    vf[d] = G[base + 768];
    vg[d] = G[base + 1536];
    vo[d] = G[base + 2304];
  }
  for (int dt0 = 0; dt0 < Tc; dt0 += 8) {
#pragma unroll
    for (int u = 0; u < 8; ++u) {
      const int dt = dt0 + u;
      const int t = t0 + dt;
      float av = va[u], fv = vf[u], gv = vg[u], ov = vo[u];
      int pre = dt + 8;
      if (pre < Tc) {
        size_t base = ((size_t)(pre * B_ + b)) * NG_ + h;
        va[u] = G[base];
        vf[u] = G[base + 768];
        vg[u] = G[base + 1536];
        vo[u] = G[base + 2304];
      }
      if (LAYER == 0) {
        if (rst[t]) c = 0.f;
      }
      c = fv * c + av * gv;
      float hv = ov * mytanh(c);
      if (LAYER == 0)
        h0c[((size_t)(dt * B_ + b)) * K_ + h] = f2bf(hv);
      else
        out[((size_t)(t * B_ + b)) * K_ + h] = hv;
      if (t == S_ - 1) { hfin[ci] = hv; cfin[ci] = c; }
    }
  }
  carry[ci] = c;
}

// ---------------- host ----------------

extern "C" void kernel_launch(void* const* d_in, const int* in_sizes, int n_in,
                              void* d_out, int out_size, void* d_ws, size_t ws_size,
                              hipStream_t stream) {
  const float* x = (const float*)d_in[0];
  const float* Wih = (const float*)d_in[1];
  // d_in[2] = W_hh: provably unused (h0 == 0 always)
  const float* bih = (const float*)d_in[3];
  const float* bhh = (const float*)d_in[4];
  const int* parts = (const int*)d_in[5];

  char* ws = (char*)d_ws;
  // fixed ws region
  unsigned short* Wbf = (unsigned short*)(ws);          // 2*3072*768*2 = 9437184
  float* bias = (float*)(ws + 9437184);                 // 2*3072*4     = 24576
  int* reset = (int*)(ws + 9461760);                    // 2048*4       = 8192
  float* carry = (float*)(ws + 9469952);                // 2*49152*4    = 393216
  const size_t fixed_end = 9863168;

  float* out0 = (float*)d_out;
  float* hfin = out0 + 100663296LL;  // S*B*H
  float* cfin = hfin + 98304;        // L*B*H

  // per-chunk buffers: Ah(bf16) + h0c(bf16) + Gc(fp32 activations)
  // bytes/chunk-step = 64*768*2 *2 + 64*3072*4 = 983040
  int chunk = 8;
  const int cand[5] = {128, 64, 32, 16, 8};
  for (int i = 0; i < 5; ++i) {
    size_t need = fixed_end + (size_t)cand[i] * 983040ull;
    if (need <= ws_size) { chunk = cand[i]; break; }
  }
  size_t off = fixed_end;
  unsigned short* Ah = (unsigned short*)(ws + off); off += (size_t)chunk * 98304;
  unsigned short* h0c = (unsigned short*)(ws + off); off += (size_t)chunk * 98304;
  float* Gc = (float*)(ws + off);

  prep_w<<<4608, 256, 0, stream>>>((const float4*)Wih, (ushort4*)Wbf);
  prep_small<<<32, 256, 0, stream>>>(bih, bhh, parts, bias, reset);

  const unsigned short* W0 = Wbf;
  const unsigned short* W1 = Wbf + (size_t)NG_ * K_;
  const int nch = S_ / chunk;
  const dim3 gg(chunk * B_ / 128, NG_ / 128);

  for (int ci = 0; ci < nch; ++ci) {
    const int t0 = ci * chunk;
    cast_x<<<chunk * 48, 256, 0, stream>>>((const float4*)x, (ushort4*)Ah, t0);
    gemm_bt<<<gg, 256, 0, stream>>>(Ah, W0, bias, Gc);
    scan_kernel<0><<<768, 64, 0, stream>>>(Gc, chunk, t0, reset, carry, h0c,
                                           nullptr, hfin, cfin);
    gemm_bt<<<gg, 256, 0, stream>>>(h0c, W1, bias + NG_, Gc);
    scan_kernel<1><<<768, 64, 0, stream>>>(Gc, chunk, t0, nullptr, carry + 49152,
                                           nullptr, out0, hfin + 49152,
                                           cfin + 49152);
  }
}